// Round 18
// baseline (149.689 us; speedup 1.0000x reference)
//
#include <hip/hip_runtime.h>

typedef _Float16 f16;
typedef __attribute__((ext_vector_type(2))) _Float16 f16x2;
typedef __attribute__((ext_vector_type(4))) _Float16 f16x4;
typedef __attribute__((ext_vector_type(8))) _Float16 f16x8;
typedef __attribute__((ext_vector_type(4))) float    f32x4;
typedef __attribute__((ext_vector_type(16))) float   f32x16;
typedef __attribute__((ext_vector_type(4))) unsigned u32x4;

static constexpr int B_ = 2, N_ = 2048, E_ = 1024, H_ = 16, D_ = 64;
static constexpr int M_ = B_ * N_;   // 4096

#define MFMA16(a, b, c) __builtin_amdgcn_mfma_f32_16x16x32_f16(a, b, c, 0, 0, 0)
#define MFMA32(a, b, c) __builtin_amdgcn_mfma_f32_32x32x16_f16(a, b, c, 0, 0, 0)

// q-projection scale: 1/sqrt(D) * log2(e)  (softmax done in exp2 domain)
#define QSCALE 0.18033688011112042f

// ---------------------------------------------------------------------------
// Kernel 1: projection GEMM — attn-style staging + 2-deep prefetch, with BOTH
//   fp32 operands cast at ds_write (A = q/k/v, B = Wq/Wk/Wv raw fp32).
//   Content maps (R14/R15/R16-proven):
//     As[r][pos] = chunk pos^(r&3)       read caA = (lg^(lr&3))*8
//     Bs[r][pos] = chunk pos^((r>>1)&3)  read caB = (lg^((lr>>1)&3))*8
//   Epilogue: q -> qh (scaled), k -> kh, v -> vt[b,h,d,n]  (R6-proven).
// ---------------------------------------------------------------------------
__global__ __launch_bounds__(256) void proj_gemm(
    const float* __restrict__ q, const float* __restrict__ k, const float* __restrict__ v,
    const float* __restrict__ Wq, const float* __restrict__ Wk, const float* __restrict__ Wv,
    const float* __restrict__ bq, const float* __restrict__ bk, const float* __restrict__ bv,
    f16* __restrict__ qh, f16* __restrict__ kh, f16* __restrict__ vt)
{
    const int bid  = blockIdx.x;
    const int lin  = (bid & 7) * 96 + (bid >> 3);
    const int z    = lin >> 8;
    const int rem  = lin & 255;
    const int m0   = (rem >> 3) * 128;
    const int n0   = (rem & 7) * 128;

    const float* A    = (z == 0) ? q  : (z == 1) ? k  : v;   // fp32 [M][E]
    const float* W    = (z == 0) ? Wq : (z == 1) ? Wk : Wv;  // fp32 [E][E]
    const float* bias = (z == 0) ? bq : (z == 1) ? bk : bv;

    __shared__ f16 As[2][128][32];
    __shared__ f16 Bs[2][128][32];

    const int tid  = threadIdx.x;
    const int lane = tid & 63, w = tid >> 6;
    const int lr = lane & 15, lg = lane >> 4;
    const int wm = (w >> 1) * 64, wn = (w & 1) * 64;

    const int srow = tid >> 1;
    const int h    = tid & 1;
    const int sA3  = srow & 3;
    const int cA0  = (2 * h)     ^ sA3;
    const int cA1  = (2 * h + 1) ^ sA3;
    const int sB3  = (srow >> 1) & 3;
    const int cB0  = (2 * h)     ^ sB3;
    const int cB1  = (2 * h + 1) ^ sB3;
    const float* ag = A + (size_t)(m0 + srow) * E_;
    const float* bg = W + (size_t)(n0 + srow) * E_;

    const int caA = (lg ^ (lr & 3)) * 8;
    const int caB = (lg ^ ((lr >> 1) & 3)) * 8;

    f32x4 acc[4][4];
#pragma unroll
    for (int i = 0; i < 4; i++)
#pragma unroll
        for (int j = 0; j < 4; j++) acc[i][j] = (f32x4){0.f, 0.f, 0.f, 0.f};

    // prologue: tile 0 -> _e regs, tile 1 -> _o regs
    f32x4 aA0_e = *(const f32x4*)(ag + 8 * cA0);
    f32x4 aA1_e = *(const f32x4*)(ag + 8 * cA0 + 4);
    f32x4 aB0_e = *(const f32x4*)(ag + 8 * cA1);
    f32x4 aB1_e = *(const f32x4*)(ag + 8 * cA1 + 4);
    f32x4 bA0_e = *(const f32x4*)(bg + 8 * cB0);
    f32x4 bA1_e = *(const f32x4*)(bg + 8 * cB0 + 4);
    f32x4 bB0_e = *(const f32x4*)(bg + 8 * cB1);
    f32x4 bB1_e = *(const f32x4*)(bg + 8 * cB1 + 4);
    f32x4 aA0_o = *(const f32x4*)(ag + 32 + 8 * cA0);
    f32x4 aA1_o = *(const f32x4*)(ag + 32 + 8 * cA0 + 4);
    f32x4 aB0_o = *(const f32x4*)(ag + 32 + 8 * cA1);
    f32x4 aB1_o = *(const f32x4*)(ag + 32 + 8 * cA1 + 4);
    f32x4 bA0_o = *(const f32x4*)(bg + 32 + 8 * cB0);
    f32x4 bA1_o = *(const f32x4*)(bg + 32 + 8 * cB0 + 4);
    f32x4 bB0_o = *(const f32x4*)(bg + 32 + 8 * cB1);
    f32x4 bB1_o = *(const f32x4*)(bg + 32 + 8 * cB1 + 4);

#define STAGE(BUF, A0, A1, A2, A3, B0, B1, B2, B3)                          \
    {                                                                       \
        f16x8 w0, w1, w2, w3;                                               \
        _Pragma("unroll")                                                   \
        for (int j = 0; j < 4; j++) {                                       \
            w0[j] = (f16)A0[j]; w0[4 + j] = (f16)A1[j];                     \
            w1[j] = (f16)A2[j]; w1[4 + j] = (f16)A3[j];                     \
            w2[j] = (f16)B0[j]; w2[4 + j] = (f16)B1[j];                     \
            w3[j] = (f16)B2[j]; w3[4 + j] = (f16)B3[j];                     \
        }                                                                   \
        *(f16x8*)&As[BUF][srow][16 * h]     = w0;                           \
        *(f16x8*)&As[BUF][srow][16 * h + 8] = w1;                           \
        *(f16x8*)&Bs[BUF][srow][16 * h]     = w2;                           \
        *(f16x8*)&Bs[BUF][srow][16 * h + 8] = w3;                           \
    }

#define COMPUTE(BUF)                                                        \
    {                                                                       \
        f16x8 af[4], bfr[4];                                                \
        _Pragma("unroll")                                                   \
        for (int ms = 0; ms < 4; ms++)                                      \
            af[ms]  = *(const f16x8*)&As[BUF][wm + ms * 16 + lr][caA];      \
        _Pragma("unroll")                                                   \
        for (int ns = 0; ns < 4; ns++)                                      \
            bfr[ns] = *(const f16x8*)&Bs[BUF][wn + ns * 16 + lr][caB];      \
        __builtin_amdgcn_s_setprio(1);                                      \
        _Pragma("unroll")                                                   \
        for (int ms = 0; ms < 4; ms++)                                      \
            _Pragma("unroll")                                               \
            for (int ns = 0; ns < 4; ns++)                                  \
                acc[ms][ns] = MFMA16(af[ms], bfr[ns], acc[ms][ns]);         \
        __builtin_amdgcn_s_setprio(0);                                      \
    }

    constexpr int NT = E_ / 32;   // 32

    for (int t = 0; t < NT; t += 2) {
        STAGE(0, aA0_e, aA1_e, aB0_e, aB1_e, bA0_e, bA1_e, bB0_e, bB1_e);
        if (t + 2 < NT) {
            const float* an = ag + (t + 2) * 32;
            const float* bn = bg + (t + 2) * 32;
            aA0_e = *(const f32x4*)(an + 8 * cA0);
            aA1_e = *(const f32x4*)(an + 8 * cA0 + 4);
            aB0_e = *(const f32x4*)(an + 8 * cA1);
            aB1_e = *(const f32x4*)(an + 8 * cA1 + 4);
            bA0_e = *(const f32x4*)(bn + 8 * cB0);
            bA1_e = *(const f32x4*)(bn + 8 * cB0 + 4);
            bB0_e = *(const f32x4*)(bn + 8 * cB1);
            bB1_e = *(const f32x4*)(bn + 8 * cB1 + 4);
        }
        __syncthreads();
        COMPUTE(0);

        STAGE(1, aA0_o, aA1_o, aB0_o, aB1_o, bA0_o, bA1_o, bB0_o, bB1_o);
        if (t + 3 < NT) {
            const float* an = ag + (t + 3) * 32;
            const float* bn = bg + (t + 3) * 32;
            aA0_o = *(const f32x4*)(an + 8 * cA0);
            aA1_o = *(const f32x4*)(an + 8 * cA0 + 4);
            aB0_o = *(const f32x4*)(an + 8 * cA1);
            aB1_o = *(const f32x4*)(an + 8 * cA1 + 4);
            bA0_o = *(const f32x4*)(bn + 8 * cB0);
            bA1_o = *(const f32x4*)(bn + 8 * cB0 + 4);
            bB0_o = *(const f32x4*)(bn + 8 * cB1);
            bB1_o = *(const f32x4*)(bn + 8 * cB1 + 4);
        }
        __syncthreads();
        COMPUTE(1);
    }
#undef STAGE
#undef COMPUTE

    const float oscale = (z == 0) ? QSCALE : 1.0f;
#pragma unroll
    for (int ms = 0; ms < 4; ms++) {
        const int mbase = m0 + wm + ms * 16 + lg * 4;
#pragma unroll
        for (int ns = 0; ns < 4; ns++) {
            const int n  = n0 + wn + ns * 16 + lr;
            const float bn = bias[n];
            const int hh = n >> 6, dd = n & 63;
#pragma unroll
            for (int r = 0; r < 4; r++) {
                const float val = (acc[ms][ns][r] + bn) * oscale;
                const int mm = mbase + r;
                const int bb = mm >> 11;
                const int nn = mm & (N_ - 1);
                if (z == 2) {
                    vt[((size_t)(bb * H_ + hh) * D_ + dd) * N_ + nn] = (f16)val;
                } else {
                    f16* dst = (z == 0) ? qh : kh;
                    dst[((size_t)(bb * H_ + hh) * N_ + nn) * D_ + dd] = (f16)val;
                }
            }
        }
    }
}

// ---------------------------------------------------------------------------
// Kernel 2: flash attention — R6/R12/R16-proven structure. Cross-half ops are
//  __shfl_xor(.,32) ONLY (permlane32_swap(x,x) with aliased operands is a
//  degenerate in-place rotate — both outputs identical — R3/R11/R17 failures).
// ---------------------------------------------------------------------------
__global__ __launch_bounds__(256) void attn_kernel(
    const f16* __restrict__ qh, const f16* __restrict__ kh,
    const f16* __restrict__ vt, f16* __restrict__ ao)
{
    const int bid = blockIdx.x;
    const int swz = (bid & 7) * 64 + (bid >> 3);   // 512 blocks, 8 XCDs
    const int qt = swz & 15;            // 16 q-tiles of 128 rows
    const int bh = swz >> 4;            // 0..31

    const int tid = threadIdx.x;
    const int w = tid >> 6, lane = tid & 63;
    const int l31 = lane & 31;
    const bool hi = (lane >> 5) != 0;
    const int hib = hi ? 1 : 0;

    const f16* qp = qh + (size_t)bh * N_ * D_;
    const f16* kp = kh + (size_t)bh * N_ * D_;
    const f16* vp = vt + (size_t)bh * D_ * N_;

    const int qrow = qt * 128 + w * 32 + l31;

    f16x8 qf[4];
#pragma unroll
    for (int ks = 0; ks < 4; ks++)
        qf[ks] = *(const f16x8*)&qp[(size_t)qrow * D_ + ks * 16 + hib * 8];

    __shared__ f16 Ks[2][64][64];   // [kv][d], swizzled
    __shared__ f16 Vs[2][64][64];   // [d][kv], swizzled

    const int srow = tid >> 3;          // 0..31
    const int sch  = tid & 7;
    const int ssl  = (sch ^ (srow & 7)) * 8;

    const f16* kg0 = kp + (size_t)srow * D_ + sch * 8;
    const f16* kg1 = kg0 + (size_t)32 * D_;
    const f16* vg0 = vp + (size_t)srow * N_ + sch * 8;
    const f16* vg1 = vg0 + (size_t)32 * N_;

    f32x16 oT0 = {0.f,0.f,0.f,0.f,0.f,0.f,0.f,0.f,0.f,0.f,0.f,0.f,0.f,0.f,0.f,0.f};
    f32x16 oT1 = oT0;
    float mrun = -3.0e38f, lrun = 0.f;

    f16x8 kr0 = *(const f16x8*)(kg0);
    f16x8 kr1 = *(const f16x8*)(kg1);
    f16x8 vr0 = *(const f16x8*)(vg0);
    f16x8 vr1 = *(const f16x8*)(vg1);

    constexpr int NT = N_ / 64;         // 32
    int cur = 0;

    for (int t = 0; t < NT; ++t) {
        *(f16x8*)&Ks[cur][srow     ][ssl] = kr0;
        *(f16x8*)&Ks[cur][srow + 32][ssl] = kr1;
        *(f16x8*)&Vs[cur][srow     ][ssl] = vr0;
        *(f16x8*)&Vs[cur][srow + 32][ssl] = vr1;
        if (t + 1 < NT) {
            kr0 = *(const f16x8*)(kg0 + (size_t)(t + 1) * 64 * D_);
            kr1 = *(const f16x8*)(kg1 + (size_t)(t + 1) * 64 * D_);
            vr0 = *(const f16x8*)(vg0 + (t + 1) * 64);
            vr1 = *(const f16x8*)(vg1 + (t + 1) * 64);
        }
        __syncthreads();

        // ---- S^T = K . Q^T ----
        f32x16 sA = {0.f,0.f,0.f,0.f,0.f,0.f,0.f,0.f,0.f,0.f,0.f,0.f,0.f,0.f,0.f,0.f};
        f32x16 sB = sA;
        __builtin_amdgcn_s_setprio(1);
#pragma unroll
        for (int ks = 0; ks < 4; ks++) {
            const int c = (ks * 2 + hib) ^ (l31 & 7);
            const f16x8 kfA = *(const f16x8*)&Ks[cur][l31     ][c * 8];
            const f16x8 kfB = *(const f16x8*)&Ks[cur][l31 + 32][c * 8];
            sA = MFMA32(kfA, qf[ks], sA);
            sB = MFMA32(kfB, qf[ks], sB);
        }
        __builtin_amdgcn_s_setprio(0);

        // ---- tile max (max3 triples) + defer-max ----
        float t16[16];
#pragma unroll
        for (int r = 0; r < 16; r++) t16[r] = fmaxf(sA[r], sB[r]);
        const float u0 = fmaxf(fmaxf(t16[0],  t16[1]),  t16[2]);
        const float u1 = fmaxf(fmaxf(t16[3],  t16[4]),  t16[5]);
        const float u2 = fmaxf(fmaxf(t16[6],  t16[7]),  t16[8]);
        const float u3 = fmaxf(fmaxf(t16[9],  t16[10]), t16[11]);
        const float u4 = fmaxf(fmaxf(t16[12], t16[13]), t16[14]);
        const float v0 = fmaxf(fmaxf(u0, u1), u2);
        const float v1 = fmaxf(fmaxf(u3, u4), t16[15]);
        const float tmax = fmaxf(v0, v1);
        const float pmax = fmaxf(tmax, __shfl_xor(tmax, 32));

        if (!__all(pmax - mrun <= 8.0f)) {
            const float mnew = fmaxf(mrun, pmax);
            const float alpha = __builtin_amdgcn_exp2f(mrun - mnew);
            mrun = mnew;
            lrun *= alpha;
#pragma unroll
            for (int r = 0; r < 16; r++) { oT0[r] *= alpha; oT1[r] *= alpha; }
        }

        float p0 = 0.f, p1 = 0.f, p2 = 0.f, p3 = 0.f;
#pragma unroll
        for (int r = 0; r < 16; r += 4) {
            sA[r]   = __builtin_amdgcn_exp2f(sA[r]   - mrun); p0 += sA[r];
            sA[r+1] = __builtin_amdgcn_exp2f(sA[r+1] - mrun); p1 += sA[r+1];
            sA[r+2] = __builtin_amdgcn_exp2f(sA[r+2] - mrun); p2 += sA[r+2];
            sA[r+3] = __builtin_amdgcn_exp2f(sA[r+3] - mrun); p3 += sA[r+3];
        }
#pragma unroll
        for (int r = 0; r < 16; r += 4) {
            sB[r]   = __builtin_amdgcn_exp2f(sB[r]   - mrun); p0 += sB[r];
            sB[r+1] = __builtin_amdgcn_exp2f(sB[r+1] - mrun); p1 += sB[r+1];
            sB[r+2] = __builtin_amdgcn_exp2f(sB[r+2] - mrun); p2 += sB[r+2];
            sB[r+3] = __builtin_amdgcn_exp2f(sB[r+3] - mrun); p3 += sB[r+3];
        }
        float lsum = (p0 + p1) + (p2 + p3);
        lsum += __shfl_xor(lsum, 32);
        lrun += lsum;

        // ---- P -> B-frag via cvt_pkrtz + shfl_xor(32) + select (PROVEN) ----
        __builtin_amdgcn_s_setprio(1);
#define PVSTEP(PP0,PP1,PP2,PP3,PP4,PP5,PP6,PP7, KSI)                                   \
        {                                                                              \
            const unsigned w0 = __builtin_bit_cast(unsigned, __builtin_amdgcn_cvt_pkrtz(PP0, PP1)); \
            const unsigned w1 = __builtin_bit_cast(unsigned, __builtin_amdgcn_cvt_pkrtz(PP2, PP3)); \
            const unsigned w2 = __builtin_bit_cast(unsigned, __builtin_amdgcn_cvt_pkrtz(PP4, PP5)); \
            const unsigned w3 = __builtin_bit_cast(unsigned, __builtin_amdgcn_cvt_pkrtz(PP6, PP7)); \
            const unsigned x0 = (unsigned)__shfl_xor((int)w0, 32);                     \
            const unsigned x1 = (unsigned)__shfl_xor((int)w1, 32);                     \
            const unsigned x2 = (unsigned)__shfl_xor((int)w2, 32);                     \
            const unsigned x3 = (unsigned)__shfl_xor((int)w3, 32);                     \
            u32x4 pw;                                                                  \
            pw[0] = hi ? x2 : w0;                                                      \
            pw[1] = hi ? x3 : w1;                                                      \
            pw[2] = hi ? w2 : x0;                                                      \
            pw[3] = hi ? w3 : x1;                                                      \
            const f16x8 pa = __builtin_bit_cast(f16x8, pw);                            \
            const int c = ((KSI) * 2 + hib) ^ (l31 & 7);                               \
            const f16x8 vf0 = *(const f16x8*)&Vs[cur][l31     ][c * 8];                \
            const f16x8 vf1 = *(const f16x8*)&Vs[cur][l31 + 32][c * 8];                \
            oT0 = MFMA32(vf0, pa, oT0);                                                \
            oT1 = MFMA32(vf1, pa, oT1);                                                \
        }
        PVSTEP(sA[0],sA[1],sA[2],sA[3],sA[4],sA[5],sA[6],sA[7], 0)
        PVSTEP(sA[8],sA[9],sA[10],sA[11],sA[12],sA[13],sA[14],sA[15], 1)
        PVSTEP(sB[0],sB[1],sB[2],sB[3],sB[4],sB[5],sB[6],sB[7], 2)
        PVSTEP(sB[8],sB[9],sB[10],sB[11],sB[12],sB[13],sB[14],sB[15], 3)
#undef PVSTEP
        __builtin_amdgcn_s_setprio(0);

        cur ^= 1;
    }

    // ---- epilogue: O[q][d] = O^T / lrun ----
    const float inv = 1.0f / lrun;
    const int b = bh >> 4, h = bh & 15;
    f16* dst = ao + (size_t)(b * N_ + qrow) * E_ + h * 64 + hib * 4;
#pragma unroll
    for (int g = 0; g < 4; g++) {
        f16x4 o0, o1;
#pragma unroll
        for (int j = 0; j < 4; j++) {
            o0[j] = (f16)(oT0[g * 4 + j] * inv);
            o1[j] = (f16)(oT1[g * 4 + j] * inv);
        }
        *(f16x4*)&dst[8 * g]      = o0;
        *(f16x4*)&dst[8 * g + 32] = o1;
    }
}

// ---------------------------------------------------------------------------
// Kernel 3: output GEMM — attn-proven staging (reg-staged, dbuf, one barrier),
//  B = raw fp32 Wo cast at ds_write. A = f16 ao.
// ---------------------------------------------------------------------------
__global__ __launch_bounds__(256) void out_gemm(
    const f16* __restrict__ ao, const float* __restrict__ Wo,
    const float* __restrict__ bo, float* __restrict__ out)
{
    __shared__ f16 As[2][128][32];
    __shared__ f16 Bs[2][128][32];

    const int bid = blockIdx.x;
    const int lin = (bid & 7) * 32 + (bid >> 3);
    const int m0  = (lin >> 3) * 128;
    const int n0  = (lin & 7) * 128;

    const int tid  = threadIdx.x;
    const int lane = tid & 63, w = tid >> 6;
    const int lr = lane & 15, lg = lane >> 4;
    const int wm = (w >> 1) * 64, wn = (w & 1) * 64;

    const int srow = tid >> 1;
    const int h    = tid & 1;
    const int s3   = (srow >> 1) & 3;
    const int c0   = (2 * h)     ^ s3;
    const int c1   = (2 * h + 1) ^ s3;
    const f16*   agp = ao + (size_t)(m0 + srow) * E_;
    const float* bgp = Wo + (size_t)(n0 + srow) * E_;

    const int ca = (lg ^ ((lr >> 1) & 3)) * 8;

    f32x4 acc[4][4];
#pragma unroll
    for (int i = 0; i < 4; i++)
#pragma unroll
        for (int j = 0; j < 4; j++) acc[i][j] = (f32x4){0.f, 0.f, 0.f, 0.f};

    f16x8 aR0 = *(const f16x8*)(agp + 8 * c0);
    f16x8 aR1 = *(const f16x8*)(agp + 8 * c1);
    f32x4 bA0 = *(const f32x4*)(bgp + 8 * c0);
    f32x4 bA1 = *(const f32x4*)(bgp + 8 * c0 + 4);
    f32x4 bB0 = *(const f32x4*)(bgp + 8 * c1);
    f32x4 bB1 = *(const f32x4*)(bgp + 8 * c1 + 4);

    constexpr int NT = E_ / 32;
    int cur = 0;

    for (int t = 0; t < NT; ++t) {
        {
            f16x8 w2, w3;
#pragma unroll
            for (int j = 0; j < 4; j++) {
                w2[j] = (f16)bA0[j]; w2[4 + j] = (f16)bA1[j];
                w3[j] = (f16)bB0[j]; w3[4 + j] = (f16)bB1[j];
            }
            *(f16x8*)&As[cur][srow][16 * h]     = aR0;
            *(f16x8*)&As[cur][srow][16 * h + 8] = aR1;
            *(f16x8*)&Bs[cur][srow][16 * h]     = w2;
            *(f16x8*)&Bs[cur][srow][16 * h + 8] = w3;
        }
        if (t + 1 < NT) {
            const f16*   an = agp + (t + 1) * 32;
            const float* bn = bgp + (t + 1) * 32;
            aR0 = *(const f16x8*)(an + 8 * c0);
            aR1 = *(const f16x8*)(an + 8 * c1);
            bA0 = *(const f32x4*)(bn + 8 * c0);
            bA1 = *(const f32x4*)(bn + 8 * c0 + 4);
            bB0 = *(const f32x4*)(bn + 8 * c1);
            bB1 = *(const f32x4*)(bn + 8 * c1 + 4);
        }
        __syncthreads();

        f16x8 af[4], bfr[4];
#pragma unroll
        for (int ms = 0; ms < 4; ms++) af[ms]  = *(const f16x8*)&As[cur][wm + ms * 16 + lr][ca];
#pragma unroll
        for (int ns = 0; ns < 4; ns++) bfr[ns] = *(const f16x8*)&Bs[cur][wn + ns * 16 + lr][ca];
        __builtin_amdgcn_s_setprio(1);
#pragma unroll
        for (int ms = 0; ms < 4; ms++)
#pragma unroll
            for (int ns = 0; ns < 4; ns++)
                acc[ms][ns] = MFMA16(af[ms], bfr[ns], acc[ms][ns]);
        __builtin_amdgcn_s_setprio(0);

        cur ^= 1;
    }

#pragma unroll
    for (int ms = 0; ms < 4; ms++) {
        const int mbase = m0 + wm + ms * 16 + lg * 4;
#pragma unroll
        for (int ns = 0; ns < 4; ns++) {
            const int n = n0 + wn + ns * 16 + lr;
            const float bn = bo[n];
#pragma unroll
            for (int r = 0; r < 4; r++) {
                out[(size_t)(mbase + r) * E_ + n] = acc[ms][ns][r] + bn;
            }
        }
    }
}

// ---------------------------------------------------------------------------
extern "C" void kernel_launch(void* const* d_in, const int* in_sizes, int n_in,
                              void* d_out, int out_size, void* d_ws, size_t ws_size,
                              hipStream_t stream) {
    const float* q  = (const float*)d_in[0];
    const float* k  = (const float*)d_in[1];
    const float* v  = (const float*)d_in[2];
    const float* Wq = (const float*)d_in[3];
    const float* bq = (const float*)d_in[4];
    const float* Wk = (const float*)d_in[5];
    const float* bk = (const float*)d_in[6];
    const float* Wv = (const float*)d_in[7];
    const float* bv = (const float*)d_in[8];
    const float* Wo = (const float*)d_in[9];
    const float* bo = (const float*)d_in[10];
    float* out = (float*)d_out;

    char* ws = (char*)d_ws;
    f16* qh = (f16*)(ws + (size_t)32 * 1024 * 1024);
    f16* kh = (f16*)(ws + (size_t)40 * 1024 * 1024);
    f16* vt = (f16*)(ws + (size_t)48 * 1024 * 1024);
    f16* ao = (f16*)(ws + (size_t)56 * 1024 * 1024);

    proj_gemm<<<768, 256, 0, stream>>>(q, k, v, Wq, Wk, Wv, bq, bk, bv, qh, kh, vt);
    attn_kernel<<<512, 256, 0, stream>>>(qh, kh, vt, ao);
    out_gemm<<<256, 256, 0, stream>>>(ao, Wo, bo, out);
}

// Round 19
// 145.132 us; speedup vs baseline: 1.0314x; 1.0314x over previous
//
#include <hip/hip_runtime.h>

typedef _Float16 f16;
typedef __attribute__((ext_vector_type(2))) _Float16 f16x2;
typedef __attribute__((ext_vector_type(4))) _Float16 f16x4;
typedef __attribute__((ext_vector_type(8))) _Float16 f16x8;
typedef __attribute__((ext_vector_type(4))) float    f32x4;
typedef __attribute__((ext_vector_type(16))) float   f32x16;
typedef __attribute__((ext_vector_type(4))) unsigned u32x4;

static constexpr int B_ = 2, N_ = 2048, E_ = 1024, H_ = 16, D_ = 64;
static constexpr int M_ = B_ * N_;   // 4096

#define MFMA16(a, b, c) __builtin_amdgcn_mfma_f32_16x16x32_f16(a, b, c, 0, 0, 0)
#define MFMA32(a, b, c) __builtin_amdgcn_mfma_f32_32x32x16_f16(a, b, c, 0, 0, 0)

// q-projection scale: 1/sqrt(D) * log2(e)  (softmax done in exp2 domain)
#define QSCALE 0.18033688011112042f

// ---------------------------------------------------------------------------
// Kernel 1: cast the 4 weight matrices (fp32, [E,E] row-major) to f16.
// (Weights are REUSED operands -> pre-cast pays; A is single-use -> fused.)
// ---------------------------------------------------------------------------
__global__ __launch_bounds__(256) void castw_kernel(
    const float* __restrict__ Wq, const float* __restrict__ Wk,
    const float* __restrict__ Wv, const float* __restrict__ Wo,
    f16* __restrict__ dst)
{
    const int i = (blockIdx.x * 256 + threadIdx.x) * 4;
    const int which = i >> 20;                            // E*E = 2^20
    const float* s = (which == 0) ? Wq : (which == 1) ? Wk : (which == 2) ? Wv : Wo;
    const int j = i & (E_ * E_ - 1);
    const f32x4 f = *(const f32x4*)&s[j];
    f16x4 o;
    o[0] = (f16)f[0]; o[1] = (f16)f[1]; o[2] = (f16)f[2]; o[3] = (f16)f[3];
    *(f16x4*)&dst[i] = o;
}

// ---------------------------------------------------------------------------
// Kernel 2: projection GEMM — attn-style staging + 2-deep prefetch:
//   ping-pong register sets (_e/_o), loads issued 2 K-steps ahead.
//   A = raw fp32 q/k/v (cast at ds_write). B = f16 weights.
//   Content maps: As[r][pos]=chunk pos^(r&3), caA=(lg^(lr&3))*8;
//                 Bs[r][pos]=chunk pos^((r>>1)&3), caB=(lg^((lr>>1)&3))*8.
//   Epilogue: q -> qh (scaled), k -> kh, v -> vt[b,h,d,n].
// ---------------------------------------------------------------------------
__global__ __launch_bounds__(256) void proj_gemm(
    const float* __restrict__ q, const float* __restrict__ k, const float* __restrict__ v,
    const f16* __restrict__ Wb,
    const float* __restrict__ bq, const float* __restrict__ bk, const float* __restrict__ bv,
    f16* __restrict__ qh, f16* __restrict__ kh, f16* __restrict__ vt)
{
    const int bid  = blockIdx.x;
    const int lin  = (bid & 7) * 96 + (bid >> 3);
    const int z    = lin >> 8;
    const int rem  = lin & 255;
    const int m0   = (rem >> 3) * 128;
    const int n0   = (rem & 7) * 128;

    const float* A    = (z == 0) ? q  : (z == 1) ? k  : v;   // fp32 [M][E]
    const f16*   W    = Wb + (size_t)z * E_ * E_;
    const float* bias = (z == 0) ? bq : (z == 1) ? bk : bv;

    __shared__ f16 As[2][128][32];
    __shared__ f16 Bs[2][128][32];

    const int tid  = threadIdx.x;
    const int lane = tid & 63, w = tid >> 6;
    const int lr = lane & 15, lg = lane >> 4;
    const int wm = (w >> 1) * 64, wn = (w & 1) * 64;

    const int srow = tid >> 1;
    const int h    = tid & 1;
    const int sA3  = srow & 3;
    const int cA0  = (2 * h)     ^ sA3;
    const int cA1  = (2 * h + 1) ^ sA3;
    const int sB3  = (srow >> 1) & 3;
    const int cB0  = (2 * h)     ^ sB3;
    const int cB1  = (2 * h + 1) ^ sB3;
    const float* ag  = A + (size_t)(m0 + srow) * E_;
    const f16*   bgp = W + (size_t)(n0 + srow) * E_;

    const int caA = (lg ^ (lr & 3)) * 8;
    const int caB = (lg ^ ((lr >> 1) & 3)) * 8;

    f32x4 acc[4][4];
#pragma unroll
    for (int i = 0; i < 4; i++)
#pragma unroll
        for (int j = 0; j < 4; j++) acc[i][j] = (f32x4){0.f, 0.f, 0.f, 0.f};

    // prologue: tile 0 -> _e regs, tile 1 -> _o regs
    f32x4 aA0_e = *(const f32x4*)(ag + 8 * cA0);
    f32x4 aA1_e = *(const f32x4*)(ag + 8 * cA0 + 4);
    f32x4 aB0_e = *(const f32x4*)(ag + 8 * cA1);
    f32x4 aB1_e = *(const f32x4*)(ag + 8 * cA1 + 4);
    f16x8 bR0_e = *(const f16x8*)(bgp + 8 * cB0);
    f16x8 bR1_e = *(const f16x8*)(bgp + 8 * cB1);
    f32x4 aA0_o = *(const f32x4*)(ag + 32 + 8 * cA0);
    f32x4 aA1_o = *(const f32x4*)(ag + 32 + 8 * cA0 + 4);
    f32x4 aB0_o = *(const f32x4*)(ag + 32 + 8 * cA1);
    f32x4 aB1_o = *(const f32x4*)(ag + 32 + 8 * cA1 + 4);
    f16x8 bR0_o = *(const f16x8*)(bgp + 32 + 8 * cB0);
    f16x8 bR1_o = *(const f16x8*)(bgp + 32 + 8 * cB1);

#define STAGE(BUF, A0, A1, B0, B1, W0, W1)                                  \
    {                                                                       \
        f16x8 w0, w1;                                                       \
        _Pragma("unroll")                                                   \
        for (int j = 0; j < 4; j++) {                                       \
            w0[j] = (f16)A0[j]; w0[4 + j] = (f16)A1[j];                     \
            w1[j] = (f16)B0[j]; w1[4 + j] = (f16)B1[j];                     \
        }                                                                   \
        *(f16x8*)&As[BUF][srow][16 * h]     = w0;                           \
        *(f16x8*)&As[BUF][srow][16 * h + 8] = w1;                           \
        *(f16x8*)&Bs[BUF][srow][16 * h]     = W0;                           \
        *(f16x8*)&Bs[BUF][srow][16 * h + 8] = W1;                           \
    }

#define COMPUTE(BUF)                                                        \
    {                                                                       \
        f16x8 af[4], bfr[4];                                                \
        _Pragma("unroll")                                                   \
        for (int ms = 0; ms < 4; ms++)                                      \
            af[ms]  = *(const f16x8*)&As[BUF][wm + ms * 16 + lr][caA];      \
        _Pragma("unroll")                                                   \
        for (int ns = 0; ns < 4; ns++)                                      \
            bfr[ns] = *(const f16x8*)&Bs[BUF][wn + ns * 16 + lr][caB];      \
        __builtin_amdgcn_s_setprio(1);                                      \
        _Pragma("unroll")                                                   \
        for (int ms = 0; ms < 4; ms++)                                      \
            _Pragma("unroll")                                               \
            for (int ns = 0; ns < 4; ns++)                                  \
                acc[ms][ns] = MFMA16(af[ms], bfr[ns], acc[ms][ns]);         \
        __builtin_amdgcn_s_setprio(0);                                      \
    }

    constexpr int NT = E_ / 32;   // 32

    for (int t = 0; t < NT; t += 2) {
        // EVEN phase: stage tile t (in _e), issue loads for tile t+2 -> _e
        STAGE(0, aA0_e, aA1_e, aB0_e, aB1_e, bR0_e, bR1_e);
        if (t + 2 < NT) {
            const float* an = ag + (t + 2) * 32;
            const f16*   bn = bgp + (t + 2) * 32;
            aA0_e = *(const f32x4*)(an + 8 * cA0);
            aA1_e = *(const f32x4*)(an + 8 * cA0 + 4);
            aB0_e = *(const f32x4*)(an + 8 * cA1);
            aB1_e = *(const f32x4*)(an + 8 * cA1 + 4);
            bR0_e = *(const f16x8*)(bn + 8 * cB0);
            bR1_e = *(const f16x8*)(bn + 8 * cB1);
        }
        __syncthreads();
        COMPUTE(0);

        // ODD phase: stage tile t+1 (in _o), issue loads for tile t+3 -> _o
        STAGE(1, aA0_o, aA1_o, aB0_o, aB1_o, bR0_o, bR1_o);
        if (t + 3 < NT) {
            const float* an = ag + (t + 3) * 32;
            const f16*   bn = bgp + (t + 3) * 32;
            aA0_o = *(const f32x4*)(an + 8 * cA0);
            aA1_o = *(const f32x4*)(an + 8 * cA0 + 4);
            aB0_o = *(const f32x4*)(an + 8 * cA1);
            aB1_o = *(const f32x4*)(an + 8 * cA1 + 4);
            bR0_o = *(const f16x8*)(bn + 8 * cB0);
            bR1_o = *(const f16x8*)(bn + 8 * cB1);
        }
        __syncthreads();
        COMPUTE(1);
    }
#undef STAGE
#undef COMPUTE

    const float oscale = (z == 0) ? QSCALE : 1.0f;
#pragma unroll
    for (int ms = 0; ms < 4; ms++) {
        const int mbase = m0 + wm + ms * 16 + lg * 4;
#pragma unroll
        for (int ns = 0; ns < 4; ns++) {
            const int n  = n0 + wn + ns * 16 + lr;
            const float bn = bias[n];
            const int hh = n >> 6, dd = n & 63;
#pragma unroll
            for (int r = 0; r < 4; r++) {
                const float val = (acc[ms][ns][r] + bn) * oscale;
                const int mm = mbase + r;
                const int bb = mm >> 11;
                const int nn = mm & (N_ - 1);
                if (z == 2) {
                    vt[((size_t)(bb * H_ + hh) * D_ + dd) * N_ + nn] = (f16)val;
                } else {
                    f16* dst = (z == 0) ? qh : kh;
                    dst[((size_t)(bb * H_ + hh) * N_ + nn) * D_ + dd] = (f16)val;
                }
            }
        }
    }
}

// ---------------------------------------------------------------------------
// Kernel 3: flash attention — R6/R12-proven (grid 512, 4 waves, reg-staged
//  dbuf K/V with XOR ds_write swizzle, defer-max, shfl_xor cross-half ONLY).
// ---------------------------------------------------------------------------
__global__ __launch_bounds__(256) void attn_kernel(
    const f16* __restrict__ qh, const f16* __restrict__ kh,
    const f16* __restrict__ vt, f16* __restrict__ ao)
{
    const int bid = blockIdx.x;
    const int swz = (bid & 7) * 64 + (bid >> 3);   // 512 blocks, 8 XCDs
    const int qt = swz & 15;            // 16 q-tiles of 128 rows
    const int bh = swz >> 4;            // 0..31

    const int tid = threadIdx.x;
    const int w = tid >> 6, lane = tid & 63;
    const int l31 = lane & 31;
    const bool hi = (lane >> 5) != 0;
    const int hib = hi ? 1 : 0;

    const f16* qp = qh + (size_t)bh * N_ * D_;
    const f16* kp = kh + (size_t)bh * N_ * D_;
    const f16* vp = vt + (size_t)bh * D_ * N_;

    const int qrow = qt * 128 + w * 32 + l31;

    f16x8 qf[4];
#pragma unroll
    for (int ks = 0; ks < 4; ks++)
        qf[ks] = *(const f16x8*)&qp[(size_t)qrow * D_ + ks * 16 + hib * 8];

    __shared__ f16 Ks[2][64][64];   // [kv][d], swizzled
    __shared__ f16 Vs[2][64][64];   // [d][kv], swizzled

    const int srow = tid >> 3;          // 0..31
    const int sch  = tid & 7;
    const int ssl  = (sch ^ (srow & 7)) * 8;

    const f16* kg0 = kp + (size_t)srow * D_ + sch * 8;
    const f16* kg1 = kg0 + (size_t)32 * D_;
    const f16* vg0 = vp + (size_t)srow * N_ + sch * 8;
    const f16* vg1 = vg0 + (size_t)32 * N_;

    f32x16 oT0 = {0.f,0.f,0.f,0.f,0.f,0.f,0.f,0.f,0.f,0.f,0.f,0.f,0.f,0.f,0.f,0.f};
    f32x16 oT1 = oT0;
    float mrun = -3.0e38f, lrun = 0.f;

    f16x8 kr0 = *(const f16x8*)(kg0);
    f16x8 kr1 = *(const f16x8*)(kg1);
    f16x8 vr0 = *(const f16x8*)(vg0);
    f16x8 vr1 = *(const f16x8*)(vg1);

    constexpr int NT = N_ / 64;         // 32
    int cur = 0;

    for (int t = 0; t < NT; ++t) {
        *(f16x8*)&Ks[cur][srow     ][ssl] = kr0;
        *(f16x8*)&Ks[cur][srow + 32][ssl] = kr1;
        *(f16x8*)&Vs[cur][srow     ][ssl] = vr0;
        *(f16x8*)&Vs[cur][srow + 32][ssl] = vr1;
        if (t + 1 < NT) {
            kr0 = *(const f16x8*)(kg0 + (size_t)(t + 1) * 64 * D_);
            kr1 = *(const f16x8*)(kg1 + (size_t)(t + 1) * 64 * D_);
            vr0 = *(const f16x8*)(vg0 + (t + 1) * 64);
            vr1 = *(const f16x8*)(vg1 + (t + 1) * 64);
        }
        __syncthreads();

        // ---- S^T = K . Q^T ----
        f32x16 sA = {0.f,0.f,0.f,0.f,0.f,0.f,0.f,0.f,0.f,0.f,0.f,0.f,0.f,0.f,0.f,0.f};
        f32x16 sB = sA;
        __builtin_amdgcn_s_setprio(1);
#pragma unroll
        for (int ks = 0; ks < 4; ks++) {
            const int c = (ks * 2 + hib) ^ (l31 & 7);
            const f16x8 kfA = *(const f16x8*)&Ks[cur][l31     ][c * 8];
            const f16x8 kfB = *(const f16x8*)&Ks[cur][l31 + 32][c * 8];
            sA = MFMA32(kfA, qf[ks], sA);
            sB = MFMA32(kfB, qf[ks], sB);
        }
        __builtin_amdgcn_s_setprio(0);

        // ---- tile max (tree) + defer-max ----
        float t16[16];
#pragma unroll
        for (int r = 0; r < 16; r++) t16[r] = fmaxf(sA[r], sB[r]);
#pragma unroll
        for (int d = 8; d >= 1; d >>= 1)
#pragma unroll
            for (int r = 0; r < d; r++) t16[r] = fmaxf(t16[r], t16[r + d]);
        const float pmax = fmaxf(t16[0], __shfl_xor(t16[0], 32));

        if (!__all(pmax - mrun <= 8.0f)) {
            const float mnew = fmaxf(mrun, pmax);
            const float alpha = __builtin_amdgcn_exp2f(mrun - mnew);
            mrun = mnew;
            lrun *= alpha;
#pragma unroll
            for (int r = 0; r < 16; r++) { oT0[r] *= alpha; oT1[r] *= alpha; }
        }

        float p0 = 0.f, p1 = 0.f, p2 = 0.f, p3 = 0.f;
#pragma unroll
        for (int r = 0; r < 16; r += 4) {
            sA[r]   = __builtin_amdgcn_exp2f(sA[r]   - mrun); p0 += sA[r];
            sA[r+1] = __builtin_amdgcn_exp2f(sA[r+1] - mrun); p1 += sA[r+1];
            sA[r+2] = __builtin_amdgcn_exp2f(sA[r+2] - mrun); p2 += sA[r+2];
            sA[r+3] = __builtin_amdgcn_exp2f(sA[r+3] - mrun); p3 += sA[r+3];
        }
#pragma unroll
        for (int r = 0; r < 16; r += 4) {
            sB[r]   = __builtin_amdgcn_exp2f(sB[r]   - mrun); p0 += sB[r];
            sB[r+1] = __builtin_amdgcn_exp2f(sB[r+1] - mrun); p1 += sB[r+1];
            sB[r+2] = __builtin_amdgcn_exp2f(sB[r+2] - mrun); p2 += sB[r+2];
            sB[r+3] = __builtin_amdgcn_exp2f(sB[r+3] - mrun); p3 += sB[r+3];
        }
        float lsum = (p0 + p1) + (p2 + p3);
        lsum += __shfl_xor(lsum, 32);
        lrun += lsum;

        // ---- P -> B-frag via cvt_pkrtz + shfl_xor(32) + select (PROVEN) ----
        __builtin_amdgcn_s_setprio(1);
#define PVSTEP(PP0,PP1,PP2,PP3,PP4,PP5,PP6,PP7, KSI)                                   \
        {                                                                              \
            const unsigned w0 = __builtin_bit_cast(unsigned, __builtin_amdgcn_cvt_pkrtz(PP0, PP1)); \
            const unsigned w1 = __builtin_bit_cast(unsigned, __builtin_amdgcn_cvt_pkrtz(PP2, PP3)); \
            const unsigned w2 = __builtin_bit_cast(unsigned, __builtin_amdgcn_cvt_pkrtz(PP4, PP5)); \
            const unsigned w3 = __builtin_bit_cast(unsigned, __builtin_amdgcn_cvt_pkrtz(PP6, PP7)); \
            const unsigned x0 = (unsigned)__shfl_xor((int)w0, 32);                     \
            const unsigned x1 = (unsigned)__shfl_xor((int)w1, 32);                     \
            const unsigned x2 = (unsigned)__shfl_xor((int)w2, 32);                     \
            const unsigned x3 = (unsigned)__shfl_xor((int)w3, 32);                     \
            u32x4 pw;                                                                  \
            pw[0] = hi ? x2 : w0;                                                      \
            pw[1] = hi ? x3 : w1;                                                      \
            pw[2] = hi ? w2 : x0;                                                      \
            pw[3] = hi ? w3 : x1;                                                      \
            const f16x8 pa = __builtin_bit_cast(f16x8, pw);                            \
            const int c = ((KSI) * 2 + hib) ^ (l31 & 7);                               \
            const f16x8 vf0 = *(const f16x8*)&Vs[cur][l31     ][c * 8];                \
            const f16x8 vf1 = *(const f16x8*)&Vs[cur][l31 + 32][c * 8];                \
            oT0 = MFMA32(vf0, pa, oT0);                                                \
            oT1 = MFMA32(vf1, pa, oT1);                                                \
        }
        PVSTEP(sA[0],sA[1],sA[2],sA[3],sA[4],sA[5],sA[6],sA[7], 0)
        PVSTEP(sA[8],sA[9],sA[10],sA[11],sA[12],sA[13],sA[14],sA[15], 1)
        PVSTEP(sB[0],sB[1],sB[2],sB[3],sB[4],sB[5],sB[6],sB[7], 2)
        PVSTEP(sB[8],sB[9],sB[10],sB[11],sB[12],sB[13],sB[14],sB[15], 3)
#undef PVSTEP
        __builtin_amdgcn_s_setprio(0);

        cur ^= 1;
    }

    // ---- epilogue: O[q][d] = O^T / lrun ----
    const float inv = 1.0f / lrun;
    const int b = bh >> 4, h = bh & 15;
    f16* dst = ao + (size_t)(b * N_ + qrow) * E_ + h * 64 + hib * 4;
#pragma unroll
    for (int g = 0; g < 4; g++) {
        f16x4 o0, o1;
#pragma unroll
        for (int j = 0; j < 4; j++) {
            o0[j] = (f16)(oT0[g * 4 + j] * inv);
            o1[j] = (f16)(oT1[g * 4 + j] * inv);
        }
        *(f16x4*)&dst[8 * g]      = o0;
        *(f16x4*)&dst[8 * g + 32] = o1;
    }
}

// ---------------------------------------------------------------------------
// Kernel 4: output GEMM — attn-proven staging (reg-staged both operands,
//  dbuf LDS, one barrier per K-step). A = f16 ao, B = f16 Wo (pre-cast).
// ---------------------------------------------------------------------------
__global__ __launch_bounds__(256) void out_gemm(
    const f16* __restrict__ ao, const f16* __restrict__ Wo,
    const float* __restrict__ bo, float* __restrict__ out)
{
    __shared__ f16 As[2][128][32];
    __shared__ f16 Bs[2][128][32];

    const int bid = blockIdx.x;
    const int lin = (bid & 7) * 32 + (bid >> 3);
    const int m0  = (lin >> 3) * 128;
    const int n0  = (lin & 7) * 128;

    const int tid  = threadIdx.x;
    const int lane = tid & 63, w = tid >> 6;
    const int lr = lane & 15, lg = lane >> 4;
    const int wm = (w >> 1) * 64, wn = (w & 1) * 64;

    const int srow = tid >> 1;
    const int h    = tid & 1;
    const int s3   = (srow >> 1) & 3;
    const int c0   = (2 * h)     ^ s3;
    const int c1   = (2 * h + 1) ^ s3;
    const f16* agp = ao + (size_t)(m0 + srow) * E_;
    const f16* bgp = Wo + (size_t)(n0 + srow) * E_;

    const int ca = (lg ^ ((lr >> 1) & 3)) * 8;

    f32x4 acc[4][4];
#pragma unroll
    for (int i = 0; i < 4; i++)
#pragma unroll
        for (int j = 0; j < 4; j++) acc[i][j] = (f32x4){0.f, 0.f, 0.f, 0.f};

    f16x8 aR0 = *(const f16x8*)(agp + 8 * c0);
    f16x8 aR1 = *(const f16x8*)(agp + 8 * c1);
    f16x8 bR0 = *(const f16x8*)(bgp + 8 * c0);
    f16x8 bR1 = *(const f16x8*)(bgp + 8 * c1);

    constexpr int NT = E_ / 32;
    int cur = 0;

    for (int t = 0; t < NT; ++t) {
        *(f16x8*)&As[cur][srow][16 * h]     = aR0;
        *(f16x8*)&As[cur][srow][16 * h + 8] = aR1;
        *(f16x8*)&Bs[cur][srow][16 * h]     = bR0;
        *(f16x8*)&Bs[cur][srow][16 * h + 8] = bR1;
        if (t + 1 < NT) {
            const f16* an = agp + (t + 1) * 32;
            const f16* bn = bgp + (t + 1) * 32;
            aR0 = *(const f16x8*)(an + 8 * c0);
            aR1 = *(const f16x8*)(an + 8 * c1);
            bR0 = *(const f16x8*)(bn + 8 * c0);
            bR1 = *(const f16x8*)(bn + 8 * c1);
        }
        __syncthreads();

        f16x8 af[4], bfr[4];
#pragma unroll
        for (int ms = 0; ms < 4; ms++) af[ms]  = *(const f16x8*)&As[cur][wm + ms * 16 + lr][ca];
#pragma unroll
        for (int ns = 0; ns < 4; ns++) bfr[ns] = *(const f16x8*)&Bs[cur][wn + ns * 16 + lr][ca];
        __builtin_amdgcn_s_setprio(1);
#pragma unroll
        for (int ms = 0; ms < 4; ms++)
#pragma unroll
            for (int ns = 0; ns < 4; ns++)
                acc[ms][ns] = MFMA16(af[ms], bfr[ns], acc[ms][ns]);
        __builtin_amdgcn_s_setprio(0);

        cur ^= 1;
    }

#pragma unroll
    for (int ms = 0; ms < 4; ms++) {
        const int mbase = m0 + wm + ms * 16 + lg * 4;
#pragma unroll
        for (int ns = 0; ns < 4; ns++) {
            const int n = n0 + wn + ns * 16 + lr;
            const float bn = bo[n];
#pragma unroll
            for (int r = 0; r < 4; r++) {
                out[(size_t)(mbase + r) * E_ + n] = acc[ms][ns][r] + bn;
            }
        }
    }
}

// ---------------------------------------------------------------------------
extern "C" void kernel_launch(void* const* d_in, const int* in_sizes, int n_in,
                              void* d_out, int out_size, void* d_ws, size_t ws_size,
                              hipStream_t stream) {
    const float* q  = (const float*)d_in[0];
    const float* k  = (const float*)d_in[1];
    const float* v  = (const float*)d_in[2];
    const float* Wq = (const float*)d_in[3];
    const float* bq = (const float*)d_in[4];
    const float* Wk = (const float*)d_in[5];
    const float* bk = (const float*)d_in[6];
    const float* Wv = (const float*)d_in[7];
    const float* bv = (const float*)d_in[8];
    const float* Wo = (const float*)d_in[9];
    const float* bo = (const float*)d_in[10];
    float* out = (float*)d_out;

    char* ws = (char*)d_ws;
    f16* Wb = (f16*)ws;                                   //  8 MB: Wq|Wk|Wv|Wo f16
    f16* qh = (f16*)(ws + (size_t)32 * 1024 * 1024);
    f16* kh = (f16*)(ws + (size_t)40 * 1024 * 1024);
    f16* vt = (f16*)(ws + (size_t)48 * 1024 * 1024);
    f16* ao = (f16*)(ws + (size_t)56 * 1024 * 1024);

    castw_kernel<<<4096, 256, 0, stream>>>(Wq, Wk, Wv, Wo, Wb);
    proj_gemm<<<768, 256, 0, stream>>>(q, k, v, Wb, bq, bk, bv, qh, kh, vt);
    attn_kernel<<<512, 256, 0, stream>>>(qh, kh, vt, ao);
    out_gemm<<<256, 256, 0, stream>>>(ao, Wb + (size_t)3 * E_ * E_, bo, out);
}

// Round 20
// 144.473 us; speedup vs baseline: 1.0361x; 1.0046x over previous
//
#include <hip/hip_runtime.h>

typedef _Float16 f16;
typedef __attribute__((ext_vector_type(2))) _Float16 f16x2;
typedef __attribute__((ext_vector_type(4))) _Float16 f16x4;
typedef __attribute__((ext_vector_type(8))) _Float16 f16x8;
typedef __attribute__((ext_vector_type(4))) float    f32x4;
typedef __attribute__((ext_vector_type(16))) float   f32x16;
typedef __attribute__((ext_vector_type(4))) unsigned u32x4;

static constexpr int B_ = 2, N_ = 2048, E_ = 1024, H_ = 16, D_ = 64;
static constexpr int M_ = B_ * N_;   // 4096

#define MFMA16(a, b, c) __builtin_amdgcn_mfma_f32_16x16x32_f16(a, b, c, 0, 0, 0)
#define MFMA32(a, b, c) __builtin_amdgcn_mfma_f32_32x32x16_f16(a, b, c, 0, 0, 0)

// q-projection scale: 1/sqrt(D) * log2(e)  (softmax done in exp2 domain)
#define QSCALE 0.18033688011112042f

// ---------------------------------------------------------------------------
// Kernel 1: cast the 4 weight matrices (fp32, [E,E] row-major) to f16.
// ---------------------------------------------------------------------------
__global__ __launch_bounds__(256) void castw_kernel(
    const float* __restrict__ Wq, const float* __restrict__ Wk,
    const float* __restrict__ Wv, const float* __restrict__ Wo,
    f16* __restrict__ dst)
{
    const int i = (blockIdx.x * 256 + threadIdx.x) * 4;
    const int which = i >> 20;                            // E*E = 2^20
    const float* s = (which == 0) ? Wq : (which == 1) ? Wk : (which == 2) ? Wv : Wo;
    const int j = i & (E_ * E_ - 1);
    const f32x4 f = *(const f32x4*)&s[j];
    f16x4 o;
    o[0] = (f16)f[0]; o[1] = (f16)f[1]; o[2] = (f16)f[2]; o[3] = (f16)f[3];
    *(f16x4*)&dst[i] = o;
}

// ---------------------------------------------------------------------------
// Kernel 2: projection GEMM — 4-deep A prefetch (HBM ~900cy needs >=4 phases
//   of ~250cy in flight), 2-deep B prefetch (W is L2-resident ~200cy).
//   A = raw fp32 q/k/v (cast at ds_write). B = f16 weights.
//   Content maps: As[r][pos]=chunk pos^(r&3), caA=(lg^(lr&3))*8;
//                 Bs[r][pos]=chunk pos^((r>>1)&3), caB=(lg^((lr>>1)&3))*8.
// ---------------------------------------------------------------------------
__global__ __launch_bounds__(256) void proj_gemm(
    const float* __restrict__ q, const float* __restrict__ k, const float* __restrict__ v,
    const f16* __restrict__ Wb,
    const float* __restrict__ bq, const float* __restrict__ bk, const float* __restrict__ bv,
    f16* __restrict__ qh, f16* __restrict__ kh, f16* __restrict__ vt)
{
    const int bid  = blockIdx.x;
    const int lin  = (bid & 7) * 96 + (bid >> 3);
    const int z    = lin >> 8;
    const int rem  = lin & 255;
    const int m0   = (rem >> 3) * 128;
    const int n0   = (rem & 7) * 128;

    const float* A    = (z == 0) ? q  : (z == 1) ? k  : v;   // fp32 [M][E]
    const f16*   W    = Wb + (size_t)z * E_ * E_;
    const float* bias = (z == 0) ? bq : (z == 1) ? bk : bv;

    __shared__ f16 As[2][128][32];
    __shared__ f16 Bs[2][128][32];

    const int tid  = threadIdx.x;
    const int lane = tid & 63, w = tid >> 6;
    const int lr = lane & 15, lg = lane >> 4;
    const int wm = (w >> 1) * 64, wn = (w & 1) * 64;

    const int srow = tid >> 1;
    const int h    = tid & 1;
    const int sA3  = srow & 3;
    const int cA0  = (2 * h)     ^ sA3;
    const int cA1  = (2 * h + 1) ^ sA3;
    const int sB3  = (srow >> 1) & 3;
    const int cB0  = (2 * h)     ^ sB3;
    const int cB1  = (2 * h + 1) ^ sB3;
    const float* ag  = A + (size_t)(m0 + srow) * E_;
    const f16*   bgp = W + (size_t)(n0 + srow) * E_;

    const int caA = (lg ^ (lr & 3)) * 8;
    const int caB = (lg ^ ((lr >> 1) & 3)) * 8;

    f32x4 acc[4][4];
#pragma unroll
    for (int i = 0; i < 4; i++)
#pragma unroll
        for (int j = 0; j < 4; j++) acc[i][j] = (f32x4){0.f, 0.f, 0.f, 0.f};

#define ALOAD(SET, T)                                                       \
    {                                                                       \
        const float* an = ag + (T) * 32;                                    \
        aA0_##SET = *(const f32x4*)(an + 8 * cA0);                          \
        aA1_##SET = *(const f32x4*)(an + 8 * cA0 + 4);                      \
        aB0_##SET = *(const f32x4*)(an + 8 * cA1);                          \
        aB1_##SET = *(const f32x4*)(an + 8 * cA1 + 4);                      \
    }
#define BLOAD(SET, T)                                                       \
    {                                                                       \
        const f16* bn = bgp + (T) * 32;                                     \
        bR0_##SET = *(const f16x8*)(bn + 8 * cB0);                          \
        bR1_##SET = *(const f16x8*)(bn + 8 * cB1);                          \
    }

    // prologue: A tiles 0..3 -> sets 0..3; B tiles 0,1 -> e,o
    f32x4 aA0_0, aA1_0, aB0_0, aB1_0;
    f32x4 aA0_1, aA1_1, aB0_1, aB1_1;
    f32x4 aA0_2, aA1_2, aB0_2, aB1_2;
    f32x4 aA0_3, aA1_3, aB0_3, aB1_3;
    f16x8 bR0_e, bR1_e, bR0_o, bR1_o;
    ALOAD(0, 0) ALOAD(1, 1) ALOAD(2, 2) ALOAD(3, 3)
    BLOAD(e, 0) BLOAD(o, 1)

#define STAGE(BUF, A0, A1, B0, B1, W0, W1)                                  \
    {                                                                       \
        f16x8 w0, w1;                                                       \
        _Pragma("unroll")                                                   \
        for (int j = 0; j < 4; j++) {                                       \
            w0[j] = (f16)A0[j]; w0[4 + j] = (f16)A1[j];                     \
            w1[j] = (f16)B0[j]; w1[4 + j] = (f16)B1[j];                     \
        }                                                                   \
        *(f16x8*)&As[BUF][srow][16 * h]     = w0;                           \
        *(f16x8*)&As[BUF][srow][16 * h + 8] = w1;                           \
        *(f16x8*)&Bs[BUF][srow][16 * h]     = W0;                           \
        *(f16x8*)&Bs[BUF][srow][16 * h + 8] = W1;                           \
    }

#define COMPUTE(BUF)                                                        \
    {                                                                       \
        f16x8 af[4], bfr[4];                                                \
        _Pragma("unroll")                                                   \
        for (int ms = 0; ms < 4; ms++)                                      \
            af[ms]  = *(const f16x8*)&As[BUF][wm + ms * 16 + lr][caA];      \
        _Pragma("unroll")                                                   \
        for (int ns = 0; ns < 4; ns++)                                      \
            bfr[ns] = *(const f16x8*)&Bs[BUF][wn + ns * 16 + lr][caB];      \
        __builtin_amdgcn_s_setprio(1);                                      \
        _Pragma("unroll")                                                   \
        for (int ms = 0; ms < 4; ms++)                                      \
            _Pragma("unroll")                                               \
            for (int ns = 0; ns < 4; ns++)                                  \
                acc[ms][ns] = MFMA16(af[ms], bfr[ns], acc[ms][ns]);         \
        __builtin_amdgcn_s_setprio(0);                                      \
    }

    constexpr int NT = E_ / 32;   // 32

    for (int t = 0; t < NT; t += 4) {
        // phase 0: stage tile t (A set0, B e) -> buf0; prefetch A t+4, B t+2
        STAGE(0, aA0_0, aA1_0, aB0_0, aB1_0, bR0_e, bR1_e);
        if (t + 4 < NT) ALOAD(0, t + 4)
        if (t + 2 < NT) BLOAD(e, t + 2)
        __syncthreads();
        COMPUTE(0);

        // phase 1: stage tile t+1 (A set1, B o) -> buf1; prefetch A t+5, B t+3
        STAGE(1, aA0_1, aA1_1, aB0_1, aB1_1, bR0_o, bR1_o);
        if (t + 5 < NT) ALOAD(1, t + 5)
        if (t + 3 < NT) BLOAD(o, t + 3)
        __syncthreads();
        COMPUTE(1);

        // phase 2: stage tile t+2 (A set2, B e) -> buf0; prefetch A t+6, B t+4
        STAGE(0, aA0_2, aA1_2, aB0_2, aB1_2, bR0_e, bR1_e);
        if (t + 6 < NT) ALOAD(2, t + 6)
        if (t + 4 < NT) BLOAD(e, t + 4)
        __syncthreads();
        COMPUTE(0);

        // phase 3: stage tile t+3 (A set3, B o) -> buf1; prefetch A t+7, B t+5
        STAGE(1, aA0_3, aA1_3, aB0_3, aB1_3, bR0_o, bR1_o);
        if (t + 7 < NT) ALOAD(3, t + 7)
        if (t + 5 < NT) BLOAD(o, t + 5)
        __syncthreads();
        COMPUTE(1);
    }
#undef STAGE
#undef COMPUTE
#undef ALOAD
#undef BLOAD

    const float oscale = (z == 0) ? QSCALE : 1.0f;
#pragma unroll
    for (int ms = 0; ms < 4; ms++) {
        const int mbase = m0 + wm + ms * 16 + lg * 4;
#pragma unroll
        for (int ns = 0; ns < 4; ns++) {
            const int n  = n0 + wn + ns * 16 + lr;
            const float bn = bias[n];
            const int hh = n >> 6, dd = n & 63;
#pragma unroll
            for (int r = 0; r < 4; r++) {
                const float val = (acc[ms][ns][r] + bn) * oscale;
                const int mm = mbase + r;
                const int bb = mm >> 11;
                const int nn = mm & (N_ - 1);
                if (z == 2) {
                    vt[((size_t)(bb * H_ + hh) * D_ + dd) * N_ + nn] = (f16)val;
                } else {
                    f16* dst = (z == 0) ? qh : kh;
                    dst[((size_t)(bb * H_ + hh) * N_ + nn) * D_ + dd] = (f16)val;
                }
            }
        }
    }
}

// ---------------------------------------------------------------------------
// Kernel 3: flash attention — R6/R12-proven (grid 512, 4 waves, reg-staged
//  dbuf K/V with XOR ds_write swizzle, defer-max, shfl_xor cross-half ONLY).
//  UNCHANGED from R19.
// ---------------------------------------------------------------------------
__global__ __launch_bounds__(256) void attn_kernel(
    const f16* __restrict__ qh, const f16* __restrict__ kh,
    const f16* __restrict__ vt, f16* __restrict__ ao)
{
    const int bid = blockIdx.x;
    const int swz = (bid & 7) * 64 + (bid >> 3);   // 512 blocks, 8 XCDs
    const int qt = swz & 15;            // 16 q-tiles of 128 rows
    const int bh = swz >> 4;            // 0..31

    const int tid = threadIdx.x;
    const int w = tid >> 6, lane = tid & 63;
    const int l31 = lane & 31;
    const bool hi = (lane >> 5) != 0;
    const int hib = hi ? 1 : 0;

    const f16* qp = qh + (size_t)bh * N_ * D_;
    const f16* kp = kh + (size_t)bh * N_ * D_;
    const f16* vp = vt + (size_t)bh * D_ * N_;

    const int qrow = qt * 128 + w * 32 + l31;

    f16x8 qf[4];
#pragma unroll
    for (int ks = 0; ks < 4; ks++)
        qf[ks] = *(const f16x8*)&qp[(size_t)qrow * D_ + ks * 16 + hib * 8];

    __shared__ f16 Ks[2][64][64];   // [kv][d], swizzled
    __shared__ f16 Vs[2][64][64];   // [d][kv], swizzled

    const int srow = tid >> 3;          // 0..31
    const int sch  = tid & 7;
    const int ssl  = (sch ^ (srow & 7)) * 8;

    const f16* kg0 = kp + (size_t)srow * D_ + sch * 8;
    const f16* kg1 = kg0 + (size_t)32 * D_;
    const f16* vg0 = vp + (size_t)srow * N_ + sch * 8;
    const f16* vg1 = vg0 + (size_t)32 * N_;

    f32x16 oT0 = {0.f,0.f,0.f,0.f,0.f,0.f,0.f,0.f,0.f,0.f,0.f,0.f,0.f,0.f,0.f,0.f};
    f32x16 oT1 = oT0;
    float mrun = -3.0e38f, lrun = 0.f;

    f16x8 kr0 = *(const f16x8*)(kg0);
    f16x8 kr1 = *(const f16x8*)(kg1);
    f16x8 vr0 = *(const f16x8*)(vg0);
    f16x8 vr1 = *(const f16x8*)(vg1);

    constexpr int NT = N_ / 64;         // 32
    int cur = 0;

    for (int t = 0; t < NT; ++t) {
        *(f16x8*)&Ks[cur][srow     ][ssl] = kr0;
        *(f16x8*)&Ks[cur][srow + 32][ssl] = kr1;
        *(f16x8*)&Vs[cur][srow     ][ssl] = vr0;
        *(f16x8*)&Vs[cur][srow + 32][ssl] = vr1;
        if (t + 1 < NT) {
            kr0 = *(const f16x8*)(kg0 + (size_t)(t + 1) * 64 * D_);
            kr1 = *(const f16x8*)(kg1 + (size_t)(t + 1) * 64 * D_);
            vr0 = *(const f16x8*)(vg0 + (t + 1) * 64);
            vr1 = *(const f16x8*)(vg1 + (t + 1) * 64);
        }
        __syncthreads();

        // ---- S^T = K . Q^T ----
        f32x16 sA = {0.f,0.f,0.f,0.f,0.f,0.f,0.f,0.f,0.f,0.f,0.f,0.f,0.f,0.f,0.f,0.f};
        f32x16 sB = sA;
        __builtin_amdgcn_s_setprio(1);
#pragma unroll
        for (int ks = 0; ks < 4; ks++) {
            const int c = (ks * 2 + hib) ^ (l31 & 7);
            const f16x8 kfA = *(const f16x8*)&Ks[cur][l31     ][c * 8];
            const f16x8 kfB = *(const f16x8*)&Ks[cur][l31 + 32][c * 8];
            sA = MFMA32(kfA, qf[ks], sA);
            sB = MFMA32(kfB, qf[ks], sB);
        }
        __builtin_amdgcn_s_setprio(0);

        // ---- tile max (tree) + defer-max ----
        float t16[16];
#pragma unroll
        for (int r = 0; r < 16; r++) t16[r] = fmaxf(sA[r], sB[r]);
#pragma unroll
        for (int d = 8; d >= 1; d >>= 1)
#pragma unroll
            for (int r = 0; r < d; r++) t16[r] = fmaxf(t16[r], t16[r + d]);
        const float pmax = fmaxf(t16[0], __shfl_xor(t16[0], 32));

        if (!__all(pmax - mrun <= 8.0f)) {
            const float mnew = fmaxf(mrun, pmax);
            const float alpha = __builtin_amdgcn_exp2f(mrun - mnew);
            mrun = mnew;
            lrun *= alpha;
#pragma unroll
            for (int r = 0; r < 16; r++) { oT0[r] *= alpha; oT1[r] *= alpha; }
        }

        float p0 = 0.f, p1 = 0.f, p2 = 0.f, p3 = 0.f;
#pragma unroll
        for (int r = 0; r < 16; r += 4) {
            sA[r]   = __builtin_amdgcn_exp2f(sA[r]   - mrun); p0 += sA[r];
            sA[r+1] = __builtin_amdgcn_exp2f(sA[r+1] - mrun); p1 += sA[r+1];
            sA[r+2] = __builtin_amdgcn_exp2f(sA[r+2] - mrun); p2 += sA[r+2];
            sA[r+3] = __builtin_amdgcn_exp2f(sA[r+3] - mrun); p3 += sA[r+3];
        }
#pragma unroll
        for (int r = 0; r < 16; r += 4) {
            sB[r]   = __builtin_amdgcn_exp2f(sB[r]   - mrun); p0 += sB[r];
            sB[r+1] = __builtin_amdgcn_exp2f(sB[r+1] - mrun); p1 += sB[r+1];
            sB[r+2] = __builtin_amdgcn_exp2f(sB[r+2] - mrun); p2 += sB[r+2];
            sB[r+3] = __builtin_amdgcn_exp2f(sB[r+3] - mrun); p3 += sB[r+3];
        }
        float lsum = (p0 + p1) + (p2 + p3);
        lsum += __shfl_xor(lsum, 32);
        lrun += lsum;

        // ---- P -> B-frag via cvt_pkrtz + shfl_xor(32) + select (PROVEN) ----
        __builtin_amdgcn_s_setprio(1);
#define PVSTEP(PP0,PP1,PP2,PP3,PP4,PP5,PP6,PP7, KSI)                                   \
        {                                                                              \
            const unsigned w0 = __builtin_bit_cast(unsigned, __builtin_amdgcn_cvt_pkrtz(PP0, PP1)); \
            const unsigned w1 = __builtin_bit_cast(unsigned, __builtin_amdgcn_cvt_pkrtz(PP2, PP3)); \
            const unsigned w2 = __builtin_bit_cast(unsigned, __builtin_amdgcn_cvt_pkrtz(PP4, PP5)); \
            const unsigned w3 = __builtin_bit_cast(unsigned, __builtin_amdgcn_cvt_pkrtz(PP6, PP7)); \
            const unsigned x0 = (unsigned)__shfl_xor((int)w0, 32);                     \
            const unsigned x1 = (unsigned)__shfl_xor((int)w1, 32);                     \
            const unsigned x2 = (unsigned)__shfl_xor((int)w2, 32);                     \
            const unsigned x3 = (unsigned)__shfl_xor((int)w3, 32);                     \
            u32x4 pw;                                                                  \
            pw[0] = hi ? x2 : w0;                                                      \
            pw[1] = hi ? x3 : w1;                                                      \
            pw[2] = hi ? w2 : x0;                                                      \
            pw[3] = hi ? w3 : x1;                                                      \
            const f16x8 pa = __builtin_bit_cast(f16x8, pw);                            \
            const int c = ((KSI) * 2 + hib) ^ (l31 & 7);                               \
            const f16x8 vf0 = *(const f16x8*)&Vs[cur][l31     ][c * 8];                \
            const f16x8 vf1 = *(const f16x8*)&Vs[cur][l31 + 32][c * 8];                \
            oT0 = MFMA32(vf0, pa, oT0);                                                \
            oT1 = MFMA32(vf1, pa, oT1);                                                \
        }
        PVSTEP(sA[0],sA[1],sA[2],sA[3],sA[4],sA[5],sA[6],sA[7], 0)
        PVSTEP(sA[8],sA[9],sA[10],sA[11],sA[12],sA[13],sA[14],sA[15], 1)
        PVSTEP(sB[0],sB[1],sB[2],sB[3],sB[4],sB[5],sB[6],sB[7], 2)
        PVSTEP(sB[8],sB[9],sB[10],sB[11],sB[12],sB[13],sB[14],sB[15], 3)
#undef PVSTEP
        __builtin_amdgcn_s_setprio(0);

        cur ^= 1;
    }

    // ---- epilogue: O[q][d] = O^T / lrun ----
    const float inv = 1.0f / lrun;
    const int b = bh >> 4, h = bh & 15;
    f16* dst = ao + (size_t)(b * N_ + qrow) * E_ + h * 64 + hib * 4;
#pragma unroll
    for (int g = 0; g < 4; g++) {
        f16x4 o0, o1;
#pragma unroll
        for (int j = 0; j < 4; j++) {
            o0[j] = (f16)(oT0[g * 4 + j] * inv);
            o1[j] = (f16)(oT1[g * 4 + j] * inv);
        }
        *(f16x4*)&dst[8 * g]      = o0;
        *(f16x4*)&dst[8 * g + 32] = o1;
    }
}

// ---------------------------------------------------------------------------
// Kernel 4: output GEMM — attn-proven staging (reg-staged both operands,
//  dbuf LDS, one barrier per K-step). UNCHANGED from R19.
// ---------------------------------------------------------------------------
__global__ __launch_bounds__(256) void out_gemm(
    const f16* __restrict__ ao, const f16* __restrict__ Wo,
    const float* __restrict__ bo, float* __restrict__ out)
{
    __shared__ f16 As[2][128][32];
    __shared__ f16 Bs[2][128][32];

    const int bid = blockIdx.x;
    const int lin = (bid & 7) * 32 + (bid >> 3);
    const int m0  = (lin >> 3) * 128;
    const int n0  = (lin & 7) * 128;

    const int tid  = threadIdx.x;
    const int lane = tid & 63, w = tid >> 6;
    const int lr = lane & 15, lg = lane >> 4;
    const int wm = (w >> 1) * 64, wn = (w & 1) * 64;

    const int srow = tid >> 1;
    const int h    = tid & 1;
    const int s3   = (srow >> 1) & 3;
    const int c0   = (2 * h)     ^ s3;
    const int c1   = (2 * h + 1) ^ s3;
    const f16* agp = ao + (size_t)(m0 + srow) * E_;
    const f16* bgp = Wo + (size_t)(n0 + srow) * E_;

    const int ca = (lg ^ ((lr >> 1) & 3)) * 8;

    f32x4 acc[4][4];
#pragma unroll
    for (int i = 0; i < 4; i++)
#pragma unroll
        for (int j = 0; j < 4; j++) acc[i][j] = (f32x4){0.f, 0.f, 0.f, 0.f};

    f16x8 aR0 = *(const f16x8*)(agp + 8 * c0);
    f16x8 aR1 = *(const f16x8*)(agp + 8 * c1);
    f16x8 bR0 = *(const f16x8*)(bgp + 8 * c0);
    f16x8 bR1 = *(const f16x8*)(bgp + 8 * c1);

    constexpr int NT = E_ / 32;
    int cur = 0;

    for (int t = 0; t < NT; ++t) {
        *(f16x8*)&As[cur][srow][16 * h]     = aR0;
        *(f16x8*)&As[cur][srow][16 * h + 8] = aR1;
        *(f16x8*)&Bs[cur][srow][16 * h]     = bR0;
        *(f16x8*)&Bs[cur][srow][16 * h + 8] = bR1;
        if (t + 1 < NT) {
            const f16* an = agp + (t + 1) * 32;
            const f16* bn = bgp + (t + 1) * 32;
            aR0 = *(const f16x8*)(an + 8 * c0);
            aR1 = *(const f16x8*)(an + 8 * c1);
            bR0 = *(const f16x8*)(bn + 8 * c0);
            bR1 = *(const f16x8*)(bn + 8 * c1);
        }
        __syncthreads();

        f16x8 af[4], bfr[4];
#pragma unroll
        for (int ms = 0; ms < 4; ms++) af[ms]  = *(const f16x8*)&As[cur][wm + ms * 16 + lr][ca];
#pragma unroll
        for (int ns = 0; ns < 4; ns++) bfr[ns] = *(const f16x8*)&Bs[cur][wn + ns * 16 + lr][ca];
        __builtin_amdgcn_s_setprio(1);
#pragma unroll
        for (int ms = 0; ms < 4; ms++)
#pragma unroll
            for (int ns = 0; ns < 4; ns++)
                acc[ms][ns] = MFMA16(af[ms], bfr[ns], acc[ms][ns]);
        __builtin_amdgcn_s_setprio(0);

        cur ^= 1;
    }

#pragma unroll
    for (int ms = 0; ms < 4; ms++) {
        const int mbase = m0 + wm + ms * 16 + lg * 4;
#pragma unroll
        for (int ns = 0; ns < 4; ns++) {
            const int n = n0 + wn + ns * 16 + lr;
            const float bn = bo[n];
#pragma unroll
            for (int r = 0; r < 4; r++) {
                out[(size_t)(mbase + r) * E_ + n] = acc[ms][ns][r] + bn;
            }
        }
    }
}

// ---------------------------------------------------------------------------
extern "C" void kernel_launch(void* const* d_in, const int* in_sizes, int n_in,
                              void* d_out, int out_size, void* d_ws, size_t ws_size,
                              hipStream_t stream) {
    const float* q  = (const float*)d_in[0];
    const float* k  = (const float*)d_in[1];
    const float* v  = (const float*)d_in[2];
    const float* Wq = (const float*)d_in[3];
    const float* bq = (const float*)d_in[4];
    const float* Wk = (const float*)d_in[5];
    const float* bk = (const float*)d_in[6];
    const float* Wv = (const float*)d_in[7];
    const float* bv = (const float*)d_in[8];
    const float* Wo = (const float*)d_in[9];
    const float* bo = (const float*)d_in[10];
    float* out = (float*)d_out;

    char* ws = (char*)d_ws;
    f16* Wb = (f16*)ws;                                   //  8 MB: Wq|Wk|Wv|Wo f16
    f16* qh = (f16*)(ws + (size_t)32 * 1024 * 1024);
    f16* kh = (f16*)(ws + (size_t)40 * 1024 * 1024);
    f16* vt = (f16*)(ws + (size_t)48 * 1024 * 1024);
    f16* ao = (f16*)(ws + (size_t)56 * 1024 * 1024);

    castw_kernel<<<4096, 256, 0, stream>>>(Wq, Wk, Wv, Wo, Wb);
    proj_gemm<<<768, 256, 0, stream>>>(q, k, v, Wb, bq, bk, bv, qh, kh, vt);
    attn_kernel<<<512, 256, 0, stream>>>(qh, kh, vt, ao);
    out_gemm<<<256, 256, 0, stream>>>(ao, Wb + (size_t)3 * E_ * E_, bo, out);
}